// Round 8
// baseline (238.583 us; speedup 1.0000x reference)
//
#include <hip/hip_runtime.h>
#include <hip/hip_bf16.h>
#include <math.h>

#define T_TOK 2048
#define DM 768
#define DF 3072
#define NE 8
#define NTILES_MAX 24   // sum over experts of ceil(cnt/256) <= 4096/256 + 7 = 23

typedef __attribute__((ext_vector_type(4))) float f32x4;
typedef __attribute__((ext_vector_type(8))) short bf16x8;

static __device__ __forceinline__ ushort f2bf(float f) {
    union { float f; unsigned u; } x; x.f = f;
    unsigned r = x.u + 0x7fff + ((x.u >> 16) & 1);
    return (ushort)(r >> 16);
}
static __device__ __forceinline__ float bf2f(ushort u) {
    union { unsigned u; float f; } x; x.u = ((unsigned)u) << 16; return x.f;
}
static __device__ __forceinline__ unsigned pk2(float lo, float hi) {
    unsigned r;
    asm("v_cvt_pk_bf16_f32 %0, %1, %2" : "=v"(r) : "v"(lo), "v"(hi));
    return r;
}

// ---------------- LN + router (top-2) ----------------
__global__ __launch_bounds__(256) void ln_router_kernel(
    const float* __restrict__ hs, const float* __restrict__ gamma,
    const float* __restrict__ beta, const float* __restrict__ rw,
    ushort* __restrict__ xbf, float* __restrict__ topw, int* __restrict__ topi,
    int* __restrict__ counts)
{
    int t = blockIdx.x;
    int tid = threadIdx.x;
    const float* row = hs + (size_t)t * DM;
    float v[3];
    v[0] = row[tid]; v[1] = row[tid + 256]; v[2] = row[tid + 512];
    float s  = v[0] + v[1] + v[2];
    float sq = v[0]*v[0] + v[1]*v[1] + v[2]*v[2];
    #pragma unroll
    for (int off = 32; off > 0; off >>= 1) {
        s  += __shfl_down(s, off);
        sq += __shfl_down(sq, off);
    }
    __shared__ float wsum[4], wsq[4];
    __shared__ float pl[4][8];
    int lane = tid & 63, wv = tid >> 6;
    if (lane == 0) { wsum[wv] = s; wsq[wv] = sq; }
    __syncthreads();
    float tot  = wsum[0] + wsum[1] + wsum[2] + wsum[3];
    float totq = wsq[0] + wsq[1] + wsq[2] + wsq[3];
    float mu = tot * (1.0f / 768.0f);
    float var = totq * (1.0f / 768.0f) - mu * mu;
    float rstd = rsqrtf(var + 1e-5f);

    float p[8];
    #pragma unroll
    for (int e = 0; e < 8; e++) p[e] = 0.f;
    #pragma unroll
    for (int i = 0; i < 3; i++) {
        int d = tid + i * 256;
        float yv = (v[i] - mu) * rstd * gamma[d] + beta[d];
        xbf[(size_t)t * DM + d] = f2bf(yv);
        const float* r8 = rw + (size_t)d * 8;
        #pragma unroll
        for (int e = 0; e < 8; e++) p[e] += yv * r8[e];
    }
    #pragma unroll
    for (int off = 32; off > 0; off >>= 1) {
        #pragma unroll
        for (int e = 0; e < 8; e++) p[e] += __shfl_down(p[e], off);
    }
    if (lane == 0) {
        #pragma unroll
        for (int e = 0; e < 8; e++) pl[wv][e] = p[e];
    }
    __syncthreads();
    if (tid == 0) {
        float lg[8];
        #pragma unroll
        for (int e = 0; e < 8; e++) lg[e] = pl[0][e] + pl[1][e] + pl[2][e] + pl[3][e];
        int i0 = 0; float l0 = lg[0];
        #pragma unroll
        for (int e = 1; e < 8; e++) if (lg[e] > l0) { l0 = lg[e]; i0 = e; }
        int i1 = -1; float l1 = -3.4e38f;
        #pragma unroll
        for (int e = 0; e < 8; e++) if (e != i0 && lg[e] > l1) { l1 = lg[e]; i1 = e; }
        float w0 = 1.0f / (1.0f + __expf(l1 - l0));
        topi[2 * t] = i0;  topi[2 * t + 1] = i1;
        topw[2 * t] = w0;  topw[2 * t + 1] = 1.0f - w0;
        atomicAdd(&counts[i0], 1);
        atomicAdd(&counts[i1], 1);
    }
}

// ---------------- scan: build 256-row tile table ----------------
// ctl[0..7]=counts, [16..23]=cursors, [24]=ntiles
__global__ void scan_kernel(int* __restrict__ ctl, int4* __restrict__ tiles)
{
    if (threadIdx.x == 0 && blockIdx.x == 0) {
        int acc = 0, nt = 0;
        for (int e = 0; e < 8; e++) {
            int cnt = ctl[e];
            for (int m0 = 0; m0 < cnt; m0 += 256) {
                tiles[nt] = make_int4(e, acc + m0, min(256, cnt - m0), 0);
                nt++;
            }
            acc += cnt;
        }
        ctl[24] = nt;
    }
}

// ---------------- bucket fill ----------------
__global__ __launch_bounds__(256) void bucket_kernel(
    const int* __restrict__ topi, int* __restrict__ ctl,
    int* __restrict__ bucket_tok, int* __restrict__ tok_slot)
{
    int t = blockIdx.x * 256 + threadIdx.x;
    if (t >= T_TOK) return;
    int offs[8]; int acc = 0;
    #pragma unroll
    for (int e = 0; e < 8; e++) { offs[e] = acc; acc += ctl[e]; }
    #pragma unroll
    for (int k = 0; k < 2; k++) {
        int e = topi[2 * t + k];
        int pos = atomicAdd(&ctl[16 + e], 1);
        int idx = offs[e] + pos;
        bucket_tok[idx] = t;
        tok_slot[2 * t + k] = idx;
    }
}

// ---------------- bucketed MFMA GEMM, fused fp32->bf16 convert, 256x128 tile ------------
// C[M,N] = A[M,K] * W[K,N];  A: [M][K] bf16;  W: fp32 [E][K][N].
// 256x128 tile, BK=32, 8 waves (4x2: wave owns 64x64), 512 threads.
// LDS: A [2][256][32] bf16 (32K) + B [2][16][128] u32 (16K) = 48 KiB.
// A: global_load_lds, source-k-chunk XOR swizzle (conflict-free frag reads).
// B: fp32 global->reg (1 item/thread) -> v_cvt_pk_bf16_f32 -> swizzled ds_write.
// Round-4 schedule: depth-1 dbuf, vmcnt(0) drains, setprio around MFMA cluster.
template<bool SILU, bool GATHER, int NT, int SPLITS>
__global__ __launch_bounds__(512) void moe_gemm(
    const ushort* __restrict__ A, const float* __restrict__ W,
    ushort* __restrict__ C, const int* __restrict__ ctl,
    const int* __restrict__ bucket_tok, const int4* __restrict__ tiles,
    int K, int N)
{
    int bid = blockIdx.x;
    int c  = bid % (NT * SPLITS);
    int tl = bid / (NT * SPLITS);
    if (tl >= ctl[24]) return;
    int nt = c % NT;
    int sk = c / NT;
    int4 t4 = tiles[tl];
    int e = t4.x, grow0 = t4.y, rows = t4.z;
    const int Ks = K / SPLITS;
    const int kbase = sk * Ks;

    __shared__ ushort Al[2][256 * 32];
    __shared__ unsigned Bl[2][16 * 128];

    int tid = threadIdx.x, lane = tid & 63, wv = tid >> 6;   // wv 0..7
    // A source chunk swizzle: dest slot (lane&3) takes source chunk (lane&3)^((lane>>3)&3)
    int kchA = ((lane & 3) ^ ((lane >> 3) & 3)) * 8;

    const ushort* aptr[2];
    #pragma unroll
    for (int i = 0; i < 2; i++) {
        int r = wv * 32 + i * 16 + (lane >> 2);    // 0..255
        int rr = r < rows ? r : rows - 1;
        if (GATHER) aptr[i] = A + (size_t)bucket_tok[grow0 + rr] * K;
        else        aptr[i] = A + (size_t)(grow0 + rr) * K;
    }

    const float* Wb = W + (size_t)e * ((size_t)K * N);
    int n0 = nt * 128;
    int rp = tid >> 5;        // k-pair row 0..15
    int cc = tid & 31;        // col chunk (4 u32)

    f32x4 acc[4][4];
    #pragma unroll
    for (int m = 0; m < 4; m++)
        #pragma unroll
        for (int n = 0; n < 4; n++)
            acc[m][n] = (f32x4){0.f, 0.f, 0.f, 0.f};

    int wr = wv >> 1, wc = wv & 1;                 // wave grid 4x2
    int l15 = lane & 15, kq = lane >> 4;
    int xk = (kq & 1) << 4;

    float4 brg[2];

    auto stageA = [&](int buf, int k0) {
        #pragma unroll
        for (int i = 0; i < 2; i++) {
            __builtin_amdgcn_global_load_lds(
                (const __attribute__((address_space(1))) void*)(aptr[i] + k0 + kchA),
                (__attribute__((address_space(3))) void*)(&Al[buf][(wv * 32 + i * 16) * 32 + lane * 8]),
                16, 0, 0);
        }
    };
    auto bload = [&](int k0) {
        const float* s = Wb + (size_t)(k0 + 2 * rp) * N + n0 + 4 * cc;
        brg[0] = *(const float4*)s;
        brg[1] = *(const float4*)(s + N);
    };
    auto bwrite = [&](int buf) {
        uint4 r;
        r.x = pk2(brg[0].x, brg[1].x);
        r.y = pk2(brg[0].y, brg[1].y);
        r.z = pk2(brg[0].z, brg[1].z);
        r.w = pk2(brg[0].w, brg[1].w);
        *(uint4*)&Bl[buf][rp * 128 + ((4 * cc) ^ ((rp & 7) << 2))] = r;
    };
    auto compute = [&](int cur) {
        bf16x8 af[4], bfr[4];
        #pragma unroll
        for (int m = 0; m < 4; m++) {
            int row = wr * 64 + m * 16 + l15;
            af[m] = *(const bf16x8*)&Al[cur][row * 32 + ((kq ^ ((row >> 1) & 3)) << 3)];
        }
        const unsigned* Blc = &Bl[cur][0];
        #pragma unroll
        for (int n = 0; n < 4; n++) {
            int ncol = wc * 64 + n * 16 + l15;
            union { uint4 u; bf16x8 h; } cvu;
            cvu.u.x = Blc[(kq * 4 + 0) * 128 + (ncol ^ (xk | 0))];
            cvu.u.y = Blc[(kq * 4 + 1) * 128 + (ncol ^ (xk | 4))];
            cvu.u.z = Blc[(kq * 4 + 2) * 128 + (ncol ^ (xk | 8))];
            cvu.u.w = Blc[(kq * 4 + 3) * 128 + (ncol ^ (xk | 12))];
            bfr[n] = cvu.h;
        }
        __builtin_amdgcn_s_setprio(1);
        #pragma unroll
        for (int m = 0; m < 4; m++)
            #pragma unroll
            for (int n = 0; n < 4; n++)
                acc[m][n] = __builtin_amdgcn_mfma_f32_16x16x32_bf16(af[m], bfr[n], acc[m][n], 0, 0, 0);
        __builtin_amdgcn_s_setprio(0);
    };

    const int nk = Ks >> 5;
    stageA(0, kbase);
    bload(kbase);
    asm volatile("s_waitcnt vmcnt(0)" ::: "memory");
    bwrite(0);
    asm volatile("s_waitcnt lgkmcnt(0)" ::: "memory");
    __builtin_amdgcn_s_barrier();

    for (int ks = 0; ks < nk; ks++) {
        int cur = ks & 1;
        bool more = (ks + 1 < nk);
        if (more) {
            stageA(cur ^ 1, kbase + (ks + 1) * 32);
            bload(kbase + (ks + 1) * 32);
        }
        compute(cur);
        if (more) {
            asm volatile("s_waitcnt vmcnt(0)" ::: "memory");
            bwrite(cur ^ 1);
        }
        asm volatile("s_waitcnt vmcnt(0) lgkmcnt(0)" ::: "memory");
        __builtin_amdgcn_s_barrier();
    }

    // epilogue: row = (lane>>4)*4 + jj, col = lane&15
    #pragma unroll
    for (int m = 0; m < 4; m++) {
        #pragma unroll
        for (int n = 0; n < 4; n++) {
            #pragma unroll
            for (int jj = 0; jj < 4; jj++) {
                int r = wr * 64 + m * 16 + kq * 4 + jj;
                if (r < rows) {
                    float v = acc[m][n][jj];
                    if (SILU) v = v / (1.0f + __expf(-v));
                    int col = nt * 128 + wc * 64 + n * 16 + l15;
                    C[((size_t)sk * (T_TOK * 2) + grow0 + r) * N + col] = f2bf(v);
                }
            }
        }
    }
}

// ---------------- combine: out = residual + w0*sum_s y0_s + w1*sum_s y1_s ----------------
template<int SPLITS>
__global__ __launch_bounds__(256) void combine_kernel(
    const float* __restrict__ hs, const ushort* __restrict__ Yp,
    const float* __restrict__ topw, const int* __restrict__ tok_slot,
    float* __restrict__ out)
{
    int t = blockIdx.x, tid = threadIdx.x;
    int s0 = tok_slot[2 * t], s1 = tok_slot[2 * t + 1];
    float w0 = topw[2 * t], w1 = topw[2 * t + 1];
    const float* h = hs + (size_t)t * DM;
    float* o = out + (size_t)t * DM;
    #pragma unroll
    for (int i = 0; i < 3; i++) {
        int d = tid + i * 256;
        float y0 = 0.f, y1 = 0.f;
        #pragma unroll
        for (int s = 0; s < SPLITS; s++) {
            y0 += bf2f(Yp[((size_t)s * (T_TOK * 2) + s0) * DM + d]);
            y1 += bf2f(Yp[((size_t)s * (T_TOK * 2) + s1) * DM + d]);
        }
        o[d] = h[d] + w0 * y0 + w1 * y1;
    }
}

extern "C" void kernel_launch(void* const* d_in, const int* in_sizes, int n_in,
                              void* d_out, int out_size, void* d_ws, size_t ws_size,
                              hipStream_t stream)
{
    const float* hs    = (const float*)d_in[0];
    const float* gamma = (const float*)d_in[1];
    const float* beta  = (const float*)d_in[2];
    const float* rw    = (const float*)d_in[3];
    const float* w1    = (const float*)d_in[4];
    const float* w2    = (const float*)d_in[5];
    float* out = (float*)d_out;
    char* ws = (char*)d_ws;

    size_t o = 0;
    auto alc = [&](size_t b) { size_t r = o; o += (b + 255) & ~255ULL; return r; };
    int*      ctl        = (int*)(ws + alc(256));
    int4*     tiles      = (int4*)(ws + alc(NTILES_MAX * 16));
    float*    topw       = (float*)(ws + alc((size_t)T_TOK * 2 * 4));
    int*      topi       = (int*)(ws + alc((size_t)T_TOK * 2 * 4));
    int*      tok_slot   = (int*)(ws + alc((size_t)T_TOK * 2 * 4));
    int*      bucket_tok = (int*)(ws + alc((size_t)T_TOK * 2 * 4));
    ushort*   xbf        = (ushort*)(ws + alc((size_t)T_TOK * DM * 2));
    ushort*   Hg         = (ushort*)(ws + alc((size_t)T_TOK * 2 * DF * 2));
    size_t yp_off        = alc((size_t)4 * T_TOK * 2 * DM * 2);
    ushort*   Yp         = (ushort*)(ws + yp_off);
    bool can_split       = (o <= ws_size);

    hipMemsetAsync(ctl, 0, 256, stream);
    ln_router_kernel<<<T_TOK, 256, 0, stream>>>(hs, gamma, beta, rw, xbf, topw, topi, ctl);
    scan_kernel<<<1, 64, 0, stream>>>(ctl, tiles);
    bucket_kernel<<<8, 256, 0, stream>>>(topi, ctl, bucket_tok, tok_slot);

    moe_gemm<true, true, 24, 1><<<NTILES_MAX * 24, 512, 0, stream>>>(
        xbf, w1, Hg, ctl, bucket_tok, tiles, DM, DF);

    if (can_split) {
        moe_gemm<false, false, 6, 4><<<NTILES_MAX * 6 * 4, 512, 0, stream>>>(
            Hg, w2, Yp, ctl, bucket_tok, tiles, DF, DM);
        combine_kernel<4><<<T_TOK, 256, 0, stream>>>(hs, Yp, topw, tok_slot, out);
    } else {
        moe_gemm<false, false, 6, 1><<<NTILES_MAX * 6, 512, 0, stream>>>(
            Hg, w2, Yp, ctl, bucket_tok, tiles, DF, DM);
        combine_kernel<1><<<T_TOK, 256, 0, stream>>>(hs, Yp, topw, tok_slot, out);
    }
}